// Round 2
// baseline (111.404 us; speedup 1.0000x reference)
//
#include <hip/hip_runtime.h>
#include <hip/hip_bf16.h>
#include <stdint.h>

#define NASSETS 512
#define WINDOW  256
#define NBATCH  32
#define NWORDS  16      // 512 bits / 32
#define BM 128
#define BN 128
#define BK 64

typedef __attribute__((ext_vector_type(4))) float floatx4;
typedef __attribute__((ext_vector_type(8))) short shortx8;

__device__ __forceinline__ unsigned short f2bf(float f) {
    union { float f; unsigned int u; } c; c.f = f;
    unsigned int u = c.u;
    unsigned int r = (u + 0x7FFFu + ((u >> 16) & 1u)) >> 16;  // RNE
    return (unsigned short)r;
}

// async global->LDS, 16B per lane; dst is WAVE-UNIFORM base, HW adds lane*16.
// LDS generic addr low 32 bits == LDS offset on AMDGPU, so truncating cast is valid.
__device__ __forceinline__ void gload16(const void* gp, void* lp) {
    __builtin_amdgcn_global_load_lds(
        (const __attribute__((address_space(1))) void*)(uintptr_t)gp,
        (__attribute__((address_space(3))) void*)(unsigned int)(uintptr_t)lp,
        16, 0, 0);
}

// Kernel 1: per-(b,asset) stats over W, write normalized transposed bf16 Xt[b][n][w]
__global__ __launch_bounds__(256)
void normalize_kernel(const float* __restrict__ ret, short* __restrict__ Xt) {
    int tid = blockIdx.x * blockDim.x + threadIdx.x;   // b*NASSETS + n
    int b = tid >> 9;
    int n = tid & (NASSETS - 1);
    const float* col = ret + (size_t)b * WINDOW * NASSETS + n;

    double s = 0.0, ss = 0.0;
#pragma unroll 4
    for (int w = 0; w < WINDOW; ++w) {
        float x = col[(size_t)w * NASSETS];
        s += (double)x;
        ss += (double)x * (double)x;
    }
    double mean = s / (double)WINDOW;
    double var  = (ss - (double)WINDOW * mean * mean) / (double)(WINDOW - 1);
    if (var < 0.0) var = 0.0;
    double stdv = sqrt(var) + 1e-8;   // torch-style: std(centered, ddof=1) + 1e-8
    float inv = (float)(1.0 / stdv);
    float mf  = (float)mean;

    short* orow = Xt + (size_t)(b * NASSETS + n) * WINDOW;
    for (int w0 = 0; w0 < WINDOW; w0 += 8) {
        shortx8 pack;
#pragma unroll
        for (int j = 0; j < 8; ++j) {
            float x = col[(size_t)(w0 + j) * NASSETS];
            pack[j] = (short)f2bf((x - mf) * inv);
        }
        *(shortx8*)(orow + w0) = pack;
    }
}

// Kernel 2: 128x128 corr tile via MFMA bf16 (m97-style), ballot bit-pack epilogue.
// grid (4 jt, 4 it, 32 b), block 256 = 4 waves in 2x2, each wave a 64x64 subtile.
// LDS tiles [row][BK] contiguous (128 B/row), 16B slots XOR-swizzled: slot s of
// row r holds k-seg (s ^ (r&7)) so frag ds_read_b128 is 2-way max (free).
__global__ __launch_bounds__(256)
void corr_adj_kernel(const short* __restrict__ Xt, unsigned int* __restrict__ adj) {
    __shared__ __align__(16) short lsA[BM * BK];   // 16 KB
    __shared__ __align__(16) short lsB[BN * BK];   // 16 KB

    const int t    = threadIdx.x;
    const int lane = t & 63;
    const int wave = t >> 6;
    const int wi   = wave >> 1, wj = wave & 1;
    const int b  = blockIdx.z;
    const int i0 = blockIdx.y * BM;
    const int j0 = blockIdx.x * BN;

    const short* base = Xt + (size_t)b * NASSETS * WINDOW;

    const int m = lane & 15;
    const int q = lane >> 4;

    // staging geometry: instr covers 8 rows (1 KB); lane l -> row +(l>>3), slot l&7,
    // global k-seg (l&7)^(l>>3)  [since slot s of row r holds seg s^(r&7), r&7=(l>>3)]
    const int srowAdd  = lane >> 3;
    const int gsegOffS = ((lane & 7) ^ (lane >> 3)) * 8;   // in shorts

    floatx4 acc[4][4] = {};

    for (int k0 = 0; k0 < WINDOW; k0 += BK) {
        __syncthreads();   // previous iteration's frag reads complete
#pragma unroll
        for (int tt = 0; tt < 4; ++tt) {
            int ro = wave * 32 + tt * 8 + srowAdd;         // 0..127
            const short* gA = base + (size_t)(i0 + ro) * WINDOW + k0 + gsegOffS;
            const short* gB = base + (size_t)(j0 + ro) * WINDOW + k0 + gsegOffS;
            char* dA = (char*)lsA + (wave * 32 + tt * 8) * (BK * 2);
            char* dB = (char*)lsB + (wave * 32 + tt * 8) * (BK * 2);
            gload16(gA, dA);
            gload16(gB, dB);
        }
        __syncthreads();   // drains vmcnt(0) -> staged data visible

#pragma unroll
        for (int kk = 0; kk < 2; ++kk) {
            const int slot = ((kk * 4 + q) ^ (lane & 7)) * 16;   // byte offset in row
            shortx8 af[4], bf[4];
#pragma unroll
            for (int mi = 0; mi < 4; ++mi)
                af[mi] = *(const shortx8*)((char*)lsA + (wi * 64 + mi * 16 + m) * (BK * 2) + slot);
#pragma unroll
            for (int nj = 0; nj < 4; ++nj)
                bf[nj] = *(const shortx8*)((char*)lsB + (wj * 64 + nj * 16 + m) * (BK * 2) + slot);
#pragma unroll
            for (int mi = 0; mi < 4; ++mi)
#pragma unroll
                for (int nj = 0; nj < 4; ++nj)
                    acc[mi][nj] = __builtin_amdgcn_mfma_f32_16x16x32_bf16(
                        af[mi], bf[nj], acc[mi][nj], 0, 0, 0);
        }
    }

    // Epilogue: C/D layout col=lane&15, row=(lane>>4)*4+r (validated round 1).
    // Ballot bit l of frag (mi,nj,r) = (row (l>>4)*4+r, col l&15). Lane R owns
    // wave-local row R: mi=R>>4, q'=(R>>2)&3, r=R&3; word = slice q' of 2 ballots.
    const float T[3] = {0.3f * (float)WINDOW, 0.5f * (float)WINDOW, 0.7f * (float)WINDOW};
    unsigned int wout[3][2] = {{0u,0u},{0u,0u},{0u,0u}};
    const int qp = (lane >> 2) & 3;
#pragma unroll
    for (int mi = 0; mi < 4; ++mi) {
#pragma unroll
        for (int r = 0; r < 4; ++r) {
            bool act = ((lane >> 4) == mi) && ((lane & 3) == r);
#pragma unroll
            for (int th = 0; th < 3; ++th) {
                unsigned long long b0 = __ballot(fabsf(acc[mi][0][r]) > T[th]);
                unsigned long long b1 = __ballot(fabsf(acc[mi][1][r]) > T[th]);
                unsigned long long b2 = __ballot(fabsf(acc[mi][2][r]) > T[th]);
                unsigned long long b3 = __ballot(fabsf(acc[mi][3][r]) > T[th]);
                if (act) {
                    wout[th][0] = ((unsigned int)(b0 >> (qp * 16)) & 0xFFFFu)
                                | (((unsigned int)(b1 >> (qp * 16)) & 0xFFFFu) << 16);
                    wout[th][1] = ((unsigned int)(b2 >> (qp * 16)) & 0xFFFFu)
                                | (((unsigned int)(b3 >> (qp * 16)) & 0xFFFFu) << 16);
                }
            }
        }
    }

    const int grow    = i0 + wi * 64 + lane;       // global row this lane stores
    const int colbase = j0 + wj * 64;
    unsigned int dd = (unsigned int)(grow - colbase);
    if (dd < 64u) {                                 // zero the diagonal bit
        unsigned int m0 = (dd < 32u) ? ~(1u << dd) : 0xFFFFFFFFu;
        unsigned int m1 = (dd >= 32u) ? ~(1u << (dd - 32u)) : 0xFFFFFFFFu;
#pragma unroll
        for (int th = 0; th < 3; ++th) { wout[th][0] &= m0; wout[th][1] &= m1; }
    }
    const int wb = colbase >> 5;
    const size_t stride_t = (size_t)NBATCH * NASSETS * NWORDS;
    size_t rb = ((size_t)b * NASSETS + grow) * NWORDS + wb;
#pragma unroll
    for (int th = 0; th < 3; ++th) {
        adj[rb + th * stride_t]     = wout[th][0];
        adj[rb + th * stride_t + 1] = wout[th][1];
    }
}

// Kernel 3: connected components (min-label propagation + pointer jumping) + edges
__global__ __launch_bounds__(512)
void betti_kernel(const unsigned int* __restrict__ adj, float* __restrict__ out) {
    __shared__ int lab[NASSETS];
    __shared__ int changed;
    __shared__ int red[8];

    int th = blockIdx.x;
    int b  = blockIdx.y;
    int i  = threadIdx.x;
    int lane = i & 63, wv = i >> 6;

    const unsigned int* rowp =
        adj + (((size_t)th * NBATCH + b) * NASSETS + i) * NWORDS;
    unsigned int row[NWORDS];
    int deg = 0;
#pragma unroll
    for (int w = 0; w < NWORDS; ++w) {
        row[w] = rowp[w];
        deg += __popc(row[w]);
    }

    int v = deg;
#pragma unroll
    for (int off = 32; off > 0; off >>= 1) v += __shfl_down(v, off);
    if (lane == 0) red[wv] = v;
    lab[i] = i;
    __syncthreads();
    int total_deg = 0;
    if (i == 0)
        for (int k = 0; k < 8; ++k) total_deg += red[k];

    for (;;) {
        __syncthreads();
        if (i == 0) changed = 0;
        __syncthreads();
        int mlab = lab[i];
#pragma unroll
        for (int w = 0; w < NWORDS; ++w) {
            unsigned int bits = row[w];
            int basej = w * 32;
            while (bits) {
                int j = basej + __builtin_ctz(bits);
                bits &= bits - 1;
                int lj = lab[j];
                if (lj < mlab) mlab = lj;
            }
        }
        int lm = lab[mlab];
        if (lm < mlab) mlab = lm;
        __syncthreads();
        if (mlab < lab[i]) { lab[i] = mlab; changed = 1; }
        __syncthreads();
        if (!changed) break;
    }

    int isrep = (lab[i] == i) ? 1 : 0;
#pragma unroll
    for (int off = 32; off > 0; off >>= 1) isrep += __shfl_down(isrep, off);
    if (lane == 0) red[wv] = isrep;
    __syncthreads();
    if (i == 0) {
        int comps = 0;
        for (int k = 0; k < 8; ++k) comps += red[k];
        float compf = (float)comps;
        float edges = (float)total_deg * 0.5f;
        float b0 = compf / (float)NASSETS;
        float b1 = fmaxf(0.0f, edges - (float)NASSETS + compf) / (float)NASSETS;
        out[b * 6 + th * 2 + 0] = b0;
        out[b * 6 + th * 2 + 1] = b1;
    }
}

extern "C" void kernel_launch(void* const* d_in, const int* in_sizes, int n_in,
                              void* d_out, int out_size, void* d_ws, size_t ws_size,
                              hipStream_t stream) {
    const float* ret = (const float*)d_in[0];
    float* out = (float*)d_out;
    char* ws = (char*)d_ws;

    short* Xt = (short*)ws;                                       // 8 MB
    unsigned int* adj =
        (unsigned int*)(ws + (size_t)NBATCH * NASSETS * WINDOW * sizeof(short)); // 3 MB

    normalize_kernel<<<(NBATCH * NASSETS) / 256, 256, 0, stream>>>(ret, Xt);

    dim3 g2(NASSETS / BN, NASSETS / BM, NBATCH);
    corr_adj_kernel<<<g2, 256, 0, stream>>>(Xt, adj);

    dim3 g3(3, NBATCH);
    betti_kernel<<<g3, 512, 0, stream>>>(adj, out);
}

// Round 3
// 80.203 us; speedup vs baseline: 1.3890x; 1.3890x over previous
//
#include <hip/hip_runtime.h>
#include <hip/hip_bf16.h>
#include <stdint.h>

#define NASSETS 512
#define WINDOW  256
#define NBATCH  32
#define NWORDS  16      // 512 bits / 32
#define BM 128
#define BN 128
#define BK 64

typedef __attribute__((ext_vector_type(4))) float floatx4;
typedef __attribute__((ext_vector_type(8))) short shortx8;

__device__ __forceinline__ unsigned short f2bf(float f) {
    union { float f; unsigned int u; } c; c.f = f;
    unsigned int u = c.u;
    unsigned int r = (u + 0x7FFFu + ((u >> 16) & 1u)) >> 16;  // RNE
    return (unsigned short)r;
}

// async global->LDS, 16B per lane; dst is WAVE-UNIFORM base, HW adds lane*16.
__device__ __forceinline__ void gload16(const void* gp, void* lp) {
    __builtin_amdgcn_global_load_lds(
        (const __attribute__((address_space(1))) void*)(uintptr_t)gp,
        (__attribute__((address_space(3))) void*)(unsigned int)(uintptr_t)lp,
        16, 0, 0);
}

// Kernel 1 (v3): fused single-read normalize + transpose.
// grid (8 asset-groups, 32 batches), block 512. Thread (a = t&63, wc = t>>6)
// holds 32 floats of column n0+a in registers; fp32 stats via LDS reduce;
// bf16 pack -> XOR-swizzled LDS tile -> coalesced transposed writeout.
__global__ __launch_bounds__(512)
void normalize_kernel(const float* __restrict__ ret, short* __restrict__ Xt) {
    __shared__ float sred[512];
    __shared__ float ssred[512];
    __shared__ float smean[64];
    __shared__ float sinv[64];
    __shared__ __align__(16) short tile[64 * 256];   // 32 KB; row a: 32 slots x 8 shorts, slot s stored at s^(a&7)

    const int t  = threadIdx.x;
    const int a  = t & 63;
    const int wc = t >> 6;                 // 0..7, 32 w's each
    const int g  = blockIdx.x;             // asset group
    const int b  = blockIdx.y;
    const int n0 = g * 64;

    const float* base = ret + (size_t)b * WINDOW * NASSETS + n0 + a;

    float x[32];
    float s1 = 0.f, s2 = 0.f;
#pragma unroll
    for (int k = 0; k < 32; ++k) {
        x[k] = base[(size_t)(wc * 32 + k) * NASSETS];
        s1 += x[k];
        s2 += x[k] * x[k];
    }
    sred[wc * 64 + a]  = s1;
    ssred[wc * 64 + a] = s2;
    __syncthreads();

    if (t < 64) {
        float S = 0.f, S2 = 0.f;
#pragma unroll
        for (int c = 0; c < 8; ++c) { S += sred[c * 64 + t]; S2 += ssred[c * 64 + t]; }
        float mean = S / (float)WINDOW;
        float var  = (S2 - (float)WINDOW * mean * mean) / (float)(WINDOW - 1);
        if (var < 0.f) var = 0.f;
        float stdv = sqrtf(var) + 1e-8f;   // matches ref: std(ddof=1) + 1e-8
        smean[t] = mean;
        sinv[t]  = 1.0f / stdv;
    }
    __syncthreads();

    const float m  = smean[a];
    const float iv = sinv[a];

    // normalize in-register, pack bf16, store 4 swizzled 16B slots to LDS
#pragma unroll
    for (int kslot = 0; kslot < 4; ++kslot) {
        shortx8 pk;
#pragma unroll
        for (int j = 0; j < 8; ++j)
            pk[j] = (short)f2bf((x[kslot * 8 + j] - m) * iv);
        int s = wc * 4 + kslot;                        // w-seg 0..31
        int sp = s ^ (a & 7);                          // swizzled slot
        *(shortx8*)(tile + a * 256 + sp * 8) = pk;
    }
    __syncthreads();

    // coalesced transposed writeout: 2048 segs, 512 threads x 4 iters;
    // wave covers 2 consecutive Xt rows = 1 KB contiguous global.
    short* orow = Xt + ((size_t)b * NASSETS + n0) * WINDOW;
#pragma unroll
    for (int it = 0; it < 4; ++it) {
        int seg = it * 512 + t;
        int r = seg >> 5;                              // 0..63
        int s = seg & 31;
        shortx8 v = *(const shortx8*)(tile + r * 256 + (s ^ (r & 7)) * 8);
        *(shortx8*)(orow + r * WINDOW + s * 8) = v;
    }
}

// Kernel 2: 128x128 corr tile via MFMA bf16 (m97-style), ballot bit-pack epilogue.
__global__ __launch_bounds__(256)
void corr_adj_kernel(const short* __restrict__ Xt, unsigned int* __restrict__ adj) {
    __shared__ __align__(16) short lsA[BM * BK];   // 16 KB
    __shared__ __align__(16) short lsB[BN * BK];   // 16 KB

    const int t    = threadIdx.x;
    const int lane = t & 63;
    const int wave = t >> 6;
    const int wi   = wave >> 1, wj = wave & 1;
    const int b  = blockIdx.z;
    const int i0 = blockIdx.y * BM;
    const int j0 = blockIdx.x * BN;

    const short* base = Xt + (size_t)b * NASSETS * WINDOW;

    const int m = lane & 15;
    const int q = lane >> 4;

    const int srowAdd  = lane >> 3;
    const int gsegOffS = ((lane & 7) ^ (lane >> 3)) * 8;   // in shorts

    floatx4 acc[4][4] = {};

    for (int k0 = 0; k0 < WINDOW; k0 += BK) {
        __syncthreads();
#pragma unroll
        for (int tt = 0; tt < 4; ++tt) {
            int ro = wave * 32 + tt * 8 + srowAdd;
            const short* gA = base + (size_t)(i0 + ro) * WINDOW + k0 + gsegOffS;
            const short* gB = base + (size_t)(j0 + ro) * WINDOW + k0 + gsegOffS;
            char* dA = (char*)lsA + (wave * 32 + tt * 8) * (BK * 2);
            char* dB = (char*)lsB + (wave * 32 + tt * 8) * (BK * 2);
            gload16(gA, dA);
            gload16(gB, dB);
        }
        __syncthreads();

#pragma unroll
        for (int kk = 0; kk < 2; ++kk) {
            const int slot = ((kk * 4 + q) ^ (lane & 7)) * 16;
            shortx8 af[4], bf[4];
#pragma unroll
            for (int mi = 0; mi < 4; ++mi)
                af[mi] = *(const shortx8*)((char*)lsA + (wi * 64 + mi * 16 + m) * (BK * 2) + slot);
#pragma unroll
            for (int nj = 0; nj < 4; ++nj)
                bf[nj] = *(const shortx8*)((char*)lsB + (wj * 64 + nj * 16 + m) * (BK * 2) + slot);
#pragma unroll
            for (int mi = 0; mi < 4; ++mi)
#pragma unroll
                for (int nj = 0; nj < 4; ++nj)
                    acc[mi][nj] = __builtin_amdgcn_mfma_f32_16x16x32_bf16(
                        af[mi], bf[nj], acc[mi][nj], 0, 0, 0);
        }
    }

    const float T[3] = {0.3f * (float)WINDOW, 0.5f * (float)WINDOW, 0.7f * (float)WINDOW};
    unsigned int wout[3][2] = {{0u,0u},{0u,0u},{0u,0u}};
    const int qp = (lane >> 2) & 3;
#pragma unroll
    for (int mi = 0; mi < 4; ++mi) {
#pragma unroll
        for (int r = 0; r < 4; ++r) {
            bool act = ((lane >> 4) == mi) && ((lane & 3) == r);
#pragma unroll
            for (int th = 0; th < 3; ++th) {
                unsigned long long b0 = __ballot(fabsf(acc[mi][0][r]) > T[th]);
                unsigned long long b1 = __ballot(fabsf(acc[mi][1][r]) > T[th]);
                unsigned long long b2 = __ballot(fabsf(acc[mi][2][r]) > T[th]);
                unsigned long long b3 = __ballot(fabsf(acc[mi][3][r]) > T[th]);
                if (act) {
                    wout[th][0] = ((unsigned int)(b0 >> (qp * 16)) & 0xFFFFu)
                                | (((unsigned int)(b1 >> (qp * 16)) & 0xFFFFu) << 16);
                    wout[th][1] = ((unsigned int)(b2 >> (qp * 16)) & 0xFFFFu)
                                | (((unsigned int)(b3 >> (qp * 16)) & 0xFFFFu) << 16);
                }
            }
        }
    }

    const int grow    = i0 + wi * 64 + lane;
    const int colbase = j0 + wj * 64;
    unsigned int dd = (unsigned int)(grow - colbase);
    if (dd < 64u) {
        unsigned int m0 = (dd < 32u) ? ~(1u << dd) : 0xFFFFFFFFu;
        unsigned int m1 = (dd >= 32u) ? ~(1u << (dd - 32u)) : 0xFFFFFFFFu;
#pragma unroll
        for (int th = 0; th < 3; ++th) { wout[th][0] &= m0; wout[th][1] &= m1; }
    }
    const int wb = colbase >> 5;
    const size_t stride_t = (size_t)NBATCH * NASSETS * NWORDS;
    size_t rb = ((size_t)b * NASSETS + grow) * NWORDS + wb;
#pragma unroll
    for (int th = 0; th < 3; ++th) {
        adj[rb + th * stride_t]     = wout[th][0];
        adj[rb + th * stride_t + 1] = wout[th][1];
    }
}

// Kernel 3: connected components (min-label propagation + pointer jumping) + edges
__global__ __launch_bounds__(512)
void betti_kernel(const unsigned int* __restrict__ adj, float* __restrict__ out) {
    __shared__ int lab[NASSETS];
    __shared__ int changed;
    __shared__ int red[8];

    int th = blockIdx.x;
    int b  = blockIdx.y;
    int i  = threadIdx.x;
    int lane = i & 63, wv = i >> 6;

    const unsigned int* rowp =
        adj + (((size_t)th * NBATCH + b) * NASSETS + i) * NWORDS;
    unsigned int row[NWORDS];
    int deg = 0;
#pragma unroll
    for (int w = 0; w < NWORDS; ++w) {
        row[w] = rowp[w];
        deg += __popc(row[w]);
    }

    int v = deg;
#pragma unroll
    for (int off = 32; off > 0; off >>= 1) v += __shfl_down(v, off);
    if (lane == 0) red[wv] = v;
    lab[i] = i;
    __syncthreads();
    int total_deg = 0;
    if (i == 0)
        for (int k = 0; k < 8; ++k) total_deg += red[k];

    for (;;) {
        __syncthreads();
        if (i == 0) changed = 0;
        __syncthreads();
        int mlab = lab[i];
#pragma unroll
        for (int w = 0; w < NWORDS; ++w) {
            unsigned int bits = row[w];
            int basej = w * 32;
            while (bits) {
                int j = basej + __builtin_ctz(bits);
                bits &= bits - 1;
                int lj = lab[j];
                if (lj < mlab) mlab = lj;
            }
        }
        int lm = lab[mlab];
        if (lm < mlab) mlab = lm;
        __syncthreads();
        if (mlab < lab[i]) { lab[i] = mlab; changed = 1; }
        __syncthreads();
        if (!changed) break;
    }

    int isrep = (lab[i] == i) ? 1 : 0;
#pragma unroll
    for (int off = 32; off > 0; off >>= 1) isrep += __shfl_down(isrep, off);
    if (lane == 0) red[wv] = isrep;
    __syncthreads();
    if (i == 0) {
        int comps = 0;
        for (int k = 0; k < 8; ++k) comps += red[k];
        float compf = (float)comps;
        float edges = (float)total_deg * 0.5f;
        float b0 = compf / (float)NASSETS;
        float b1 = fmaxf(0.0f, edges - (float)NASSETS + compf) / (float)NASSETS;
        out[b * 6 + th * 2 + 0] = b0;
        out[b * 6 + th * 2 + 1] = b1;
    }
}

extern "C" void kernel_launch(void* const* d_in, const int* in_sizes, int n_in,
                              void* d_out, int out_size, void* d_ws, size_t ws_size,
                              hipStream_t stream) {
    const float* ret = (const float*)d_in[0];
    float* out = (float*)d_out;
    char* ws = (char*)d_ws;

    short* Xt = (short*)ws;                                       // 8 MB
    unsigned int* adj =
        (unsigned int*)(ws + (size_t)NBATCH * NASSETS * WINDOW * sizeof(short)); // 3 MB

    dim3 g1(NASSETS / 64, NBATCH);
    normalize_kernel<<<g1, 512, 0, stream>>>(ret, Xt);

    dim3 g2(NASSETS / BN, NASSETS / BM, NBATCH);
    corr_adj_kernel<<<g2, 256, 0, stream>>>(Xt, adj);

    dim3 g3(3, NBATCH);
    betti_kernel<<<g3, 512, 0, stream>>>(adj, out);
}